// Round 1
// baseline (1621.830 us; speedup 1.0000x reference)
//
#include <hip/hip_runtime.h>
#include <hip/hip_bf16.h>
#include <stdint.h>

typedef __attribute__((ext_vector_type(8))) short   short8;
typedef __attribute__((ext_vector_type(8))) __bf16  bf16x8;
typedef __attribute__((ext_vector_type(4))) float   fx4;

// async global->LDS, 16B per lane, LDS dest = wave-uniform base + lane*16
__device__ __forceinline__ void gl2lds16(const void* g, void* l) {
    __builtin_amdgcn_global_load_lds((const __attribute__((address_space(1))) void*)g,
                                     (__attribute__((address_space(3))) void*)l,
                                     16, 0, 0);
}

// ---------------------------------------------------------------------------
// x: fp32 -> bf16 elementwise (8 el / thread)
// ---------------------------------------------------------------------------
__global__ __launch_bounds__(256) void convert_fp32_bf16(
        const float* __restrict__ src, __hip_bfloat16* __restrict__ dst, long n)
{
    long i = ((long)blockIdx.x * 256 + threadIdx.x) * 8;
    if (i >= n) return;
    fx4 a = *(const fx4*)(src + i);
    fx4 b = *(const fx4*)(src + i + 4);
    union { __hip_bfloat16 h[8]; short8 v; } u;
#pragma unroll
    for (int t = 0; t < 4; ++t) {
        u.h[t]     = __float2bfloat16(a[t]);
        u.h[4 + t] = __float2bfloat16(b[t]);
    }
    *(short8*)(dst + i) = u.v;
}

// ---------------------------------------------------------------------------
// Per-slot transpose+convert: src fp32 [R][C] (slot slot_base+z of src array)
//   -> dst bf16 [C][R] (slot z of dst buffer). 64x64 tiles through LDS.
// ---------------------------------------------------------------------------
__global__ __launch_bounds__(256) void transpose_convert_kernel(
        const float* __restrict__ src, __hip_bfloat16* __restrict__ dst,
        int R, int C, int slot_base)
{
    const int z = blockIdx.z;
    const float* S = src + (long)(slot_base + z) * R * C;
    __hip_bfloat16* D = dst + (long)z * R * C;
    const int r0 = blockIdx.y * 64;
    const int c0 = blockIdx.x * 64;

    __shared__ float tile[64][68];   // +4 pad: 16B-aligned rows, conflict-benign

    const int tid = threadIdx.x;
    const int lr = tid >> 4;          // 0..15
    const int lc = (tid & 15) * 4;    // 0..60
#pragma unroll
    for (int i = 0; i < 4; ++i) {
        int rr = i * 16 + lr;
        fx4 v = *(const fx4*)(S + (long)(r0 + rr) * C + c0 + lc);
        *(fx4*)&tile[rr][lc] = v;
    }
    __syncthreads();

    const int oc  = tid >> 2;         // dst row (= src col) 0..63
    const int orc = (tid & 3) * 16;   // src-row chunk
    union { __hip_bfloat16 h[16]; short8 v[2]; } u;
#pragma unroll
    for (int t = 0; t < 16; ++t)
        u.h[t] = __float2bfloat16(tile[orc + t][oc]);
    __hip_bfloat16* dp = D + (long)(c0 + oc) * R + r0 + orc;
    ((short8*)dp)[0] = u.v[0];
    ((short8*)dp)[1] = u.v[1];
}

// ---------------------------------------------------------------------------
// bf16 GEMM, m97 structure: 128x128 tile, BK=32, mfma_f32_16x16x32_bf16,
// global_load_lds(16B) staging, 4 waves each computing a 64x64 quadrant.
// A: [rows][k] k-contiguous, per-z base A + z*a_zs, row stride a_rs.
// BT: [slot-local z][n][k] k-contiguous (row stride K).
// OM==1: C = bf16, out = relu(acc + bias). OM==0: C = fp32, out = acc + bias.
// ---------------------------------------------------------------------------
template <int OM>
__global__ __launch_bounds__(256, 2) void gemm_kernel(
        const __hip_bfloat16* __restrict__ A, long a_zs, long a_rs,
        const __hip_bfloat16* __restrict__ BT,
        const float* __restrict__ bias,
        void* __restrict__ C, long c_zs, long c_rs,
        int K, int N)
{
    const int z = blockIdx.z;
    const __hip_bfloat16* Ab = A  + (long)z * a_zs;
    const __hip_bfloat16* Bb = BT + (long)z * (long)N * K;
    const float*          bz = bias + (long)z * N;

    const int col0 = blockIdx.x * 128;
    const int row0 = blockIdx.y * 128;

    __shared__ __hip_bfloat16 As[128 * 32];   // [row][k]
    __shared__ __hip_bfloat16 Bs[128 * 32];   // [n][k]

    const int tid  = threadIdx.x;
    const int wave = tid >> 6;
    const int lane = tid & 63;
    const int wr   = wave >> 1;      // wave row 0..1
    const int wc   = wave & 1;       // wave col 0..1

    // staging: each wave issues 2 A-loads + 2 B-loads of 1KB (16 rows x 64B)
    const int i0 = wave * 2;
    const int srow = lane >> 2;             // 0..15
    const int skc  = (lane & 3) * 8;        // k offset in elements
    const __hip_bfloat16* gA0 = Ab + (long)(row0 + (i0    ) * 16 + srow) * a_rs + skc;
    const __hip_bfloat16* gA1 = Ab + (long)(row0 + (i0 + 1) * 16 + srow) * a_rs + skc;
    const __hip_bfloat16* gB0 = Bb + (long)(col0 + (i0    ) * 16 + srow) * K + skc;
    const __hip_bfloat16* gB1 = Bb + (long)(col0 + (i0 + 1) * 16 + srow) * K + skc;
    __hip_bfloat16* lA0 = As + (i0    ) * 512;
    __hip_bfloat16* lA1 = As + (i0 + 1) * 512;
    __hip_bfloat16* lB0 = Bs + (i0    ) * 512;
    __hip_bfloat16* lB1 = Bs + (i0 + 1) * 512;

    const int r = lane & 15;
    const int q = lane >> 4;

    fx4 acc[4][4];
#pragma unroll
    for (int i = 0; i < 4; ++i)
#pragma unroll
        for (int j = 0; j < 4; ++j) {
            fx4 zz = {0.f, 0.f, 0.f, 0.f};
            acc[i][j] = zz;
        }

    const bf16x8* AsV = (const bf16x8*)As;
    const bf16x8* BsV = (const bf16x8*)Bs;

    for (int kt = 0; kt < K; kt += 32) {
        gl2lds16(gA0 + kt, lA0);
        gl2lds16(gA1 + kt, lA1);
        gl2lds16(gB0 + kt, lB0);
        gl2lds16(gB1 + kt, lB1);
        __syncthreads();   // drains vmcnt, data visible

        bf16x8 af[4], bfv[4];
#pragma unroll
        for (int i = 0; i < 4; ++i)
            af[i] = AsV[(wr * 64 + i * 16 + r) * 4 + q];
#pragma unroll
        for (int j = 0; j < 4; ++j)
            bfv[j] = BsV[(wc * 64 + j * 16 + r) * 4 + q];
#pragma unroll
        for (int i = 0; i < 4; ++i)
#pragma unroll
            for (int j = 0; j < 4; ++j)
                acc[i][j] = __builtin_amdgcn_mfma_f32_16x16x32_bf16(
                        af[i], bfv[j], acc[i][j], 0, 0, 0);
        __syncthreads();   // all reads done before next stage
    }

    // epilogue: C/D layout col = lane&15, row = (lane>>4)*4 + t
#pragma unroll
    for (int j = 0; j < 4; ++j) {
        const int col = col0 + wc * 64 + j * 16 + r;
        const float bv = bz[col];
#pragma unroll
        for (int i = 0; i < 4; ++i) {
            const int rowb = row0 + wr * 64 + i * 16 + q * 4;
#pragma unroll
            for (int t = 0; t < 4; ++t) {
                float v = acc[i][j][t] + bv;
                if (OM == 1) {
                    v = fmaxf(v, 0.f);
                    ((__hip_bfloat16*)C)[(long)z * c_zs + (long)(rowb + t) * c_rs + col] =
                            __float2bfloat16(v);
                } else {
                    ((float*)C)[(long)z * c_zs + (long)(rowb + t) * c_rs + col] = v;
                }
            }
        }
    }
}

// ---------------------------------------------------------------------------
extern "C" void kernel_launch(void* const* d_in, const int* in_sizes, int n_in,
                              void* d_out, int out_size, void* d_ws, size_t ws_size,
                              hipStream_t stream)
{
    const float* x  = (const float*)d_in[0];   // [512][32][1024]
    const float* W1 = (const float*)d_in[1];   // [32][1024][4096]
    const float* b1 = (const float*)d_in[2];   // [32][4096]
    const float* W2 = (const float*)d_in[3];   // [32][4096][1024]
    const float* b2 = (const float*)d_in[4];   // [32][1024]
    float* out = (float*)d_out;                // [512][32][1024]

    constexpr int B = 512, M = 32, DI = 1024, DH = 4096, DO = 1024;

    char* ws = (char*)d_ws;
    __hip_bfloat16* xbf = (__hip_bfloat16*)ws;          // B*M*DI bf16
    const size_t xbytes = (size_t)B * M * DI * 2;        // 32 MiB

    // per-slot chunk workspace: W1T + W2T + h
    const size_t w1t_slot = (size_t)DI * DH * 2;         // 8 MiB
    const size_t w2t_slot = (size_t)DH * DO * 2;         // 8 MiB
    const size_t h_slot   = (size_t)B * DH * 2;          // 4 MiB
    const size_t perslot  = w1t_slot + w2t_slot + h_slot;

    size_t avail = ws_size > xbytes ? ws_size - xbytes : 0;
    int chunk = (int)(avail / perslot);
    if (chunk > M) chunk = M;
    if (chunk < 1) chunk = 1;

    __hip_bfloat16* w1t = (__hip_bfloat16*)(ws + xbytes);
    __hip_bfloat16* w2t = (__hip_bfloat16*)(ws + xbytes + (size_t)chunk * w1t_slot);
    __hip_bfloat16* h   = (__hip_bfloat16*)(ws + xbytes + (size_t)chunk * (w1t_slot + w2t_slot));

    // x -> bf16
    {
        long n = (long)B * M * DI;                      // 16,777,216
        int blocks = (int)((n / 8 + 255) / 256);        // 8192
        convert_fp32_bf16<<<blocks, 256, 0, stream>>>(x, xbf, n);
    }

    for (int c0 = 0; c0 < M; c0 += chunk) {
        int S = (M - c0 < chunk) ? (M - c0) : chunk;

        // W1 [DI][DH] -> W1T [DH][DI] bf16
        transpose_convert_kernel<<<dim3(DH / 64, DI / 64, S), 256, 0, stream>>>(
                W1, w1t, DI, DH, c0);
        // W2 [DH][DO] -> W2T [DO][DH] bf16
        transpose_convert_kernel<<<dim3(DO / 64, DH / 64, S), 256, 0, stream>>>(
                W2, w2t, DH, DO, c0);

        // h = relu(x @ W1 + b1)   -> bf16, slot-major [z][B][DH]
        gemm_kernel<1><<<dim3(DH / 128, B / 128, S), 256, 0, stream>>>(
                xbf + (size_t)c0 * DI, (long)DI, (long)M * DI,
                w1t, b1 + (size_t)c0 * DH,
                h, (long)B * DH, (long)DH,
                DI, DH);

        // out = h @ W2 + b2       -> fp32 [b][m][o]
        gemm_kernel<0><<<dim3(DO / 128, B / 128, S), 256, 0, stream>>>(
                h, (long)B * DH, (long)DH,
                w2t, b2 + (size_t)c0 * DO,
                out + (size_t)c0 * DO, (long)DO, (long)M * DO,
                DH, DO);
    }
}